// Round 3
// baseline (312.289 us; speedup 1.0000x reference)
//
#include <hip/hip_runtime.h>

#define N_TOK 8192
#define D_DIM 1024
#define H_DIM 2048
#define E_NUM 8
#define CAP   1280

typedef __attribute__((ext_vector_type(8))) short bf16x8;
typedef __attribute__((ext_vector_type(8))) unsigned short u16x8;
typedef __attribute__((ext_vector_type(4))) float f32x4;

__device__ inline unsigned short f2bf(float f) {
  unsigned u = __float_as_uint(f);
  u += 0x7fffu + ((u >> 16) & 1u);
  return (unsigned short)(u >> 16);
}

// Explicit drain of outstanding global_load_lds DMA before cross-wave LDS reads.
// Do NOT rely on the compiler emitting vmcnt(0) before s_barrier for LDS-DMA.
__device__ inline void vm_drain() {
  asm volatile("s_waitcnt vmcnt(0)" ::: "memory");
}

// ---------------- transpose + fp32->bf16: src (B,R,C) f32 -> dst (B,C,R) bf16
__global__ __launch_bounds__(256) void transpose_cvt(const float* __restrict__ src,
                                                     unsigned short* __restrict__ dst,
                                                     int R, int C) {
  __shared__ float tile[64][33];
  const int b = blockIdx.z;
  src += (size_t)b * R * C;
  dst += (size_t)b * R * C;
  const int c0 = blockIdx.x * 32, r0 = blockIdx.y * 64;
  const int tx = threadIdx.x & 31, ty = threadIdx.x >> 5;  // 256 = (32,8)
#pragma unroll
  for (int i = 0; i < 8; ++i)
    tile[ty + i * 8][tx] = src[(size_t)(r0 + ty + i * 8) * C + c0 + tx];
  __syncthreads();
  const int rp = threadIdx.x & 31;      // r-pair index 0..31
  const int cb = threadIdx.x >> 5;      // c base 0..7
#pragma unroll
  for (int it = 0; it < 4; ++it) {
    const int c = cb + it * 8;
    unsigned short v[2] = {f2bf(tile[2 * rp][c]), f2bf(tile[2 * rp + 1][c])};
    *reinterpret_cast<unsigned*>(dst + (size_t)(c0 + c) * R + r0 + 2 * rp) =
        *reinterpret_cast<unsigned*>(v);
  }
}

// ---------------- gating: logits = x@Wg + bg; eid=argmax; gate = softmax(logits)[eid]
__global__ __launch_bounds__(256) void gate_kernel(const float* __restrict__ x,
                                                   const float* __restrict__ Wg,
                                                   const float* __restrict__ bg,
                                                   int* __restrict__ eid,
                                                   float* __restrict__ gatew) {
  __shared__ float wg[E_NUM][D_DIM];  // transposed, 32 KiB
  const int tid = threadIdx.x;
  for (int i = tid; i < D_DIM * E_NUM; i += 256) {
    int d = i >> 3, e = i & 7;
    wg[e][d] = Wg[i];
  }
  __syncthreads();
  const int w = tid >> 6, l = tid & 63;
  const int t = blockIdx.x * 4 + w;
  const float* xr = x + (size_t)t * D_DIM;
  float acc[8] = {0, 0, 0, 0, 0, 0, 0, 0};
#pragma unroll
  for (int i = 0; i < D_DIM / 64; ++i) {
    float xv = xr[l + 64 * i];
#pragma unroll
    for (int e = 0; e < 8; ++e) acc[e] += xv * wg[e][l + 64 * i];
  }
#pragma unroll
  for (int off = 32; off >= 1; off >>= 1) {
#pragma unroll
    for (int e = 0; e < 8; ++e) acc[e] += __shfl_xor(acc[e], off);
  }
  if (l == 0) {
    float best = -1e30f;
    int bi = 0;
#pragma unroll
    for (int e = 0; e < 8; ++e) {
      acc[e] += bg[e];
      if (acc[e] > best) { best = acc[e]; bi = e; }
    }
    float s = 0.f;
#pragma unroll
    for (int e = 0; e < 8; ++e) s += __expf(acc[e] - best);
    eid[t] = bi;
    gatew[t] = 1.f / s;
  }
}

// ---------------- init tok_of to -1
__global__ void init_tok(int* __restrict__ tok_of) {
  int i = blockIdx.x * 256 + threadIdx.x;
  if (i < E_NUM * CAP) tok_of[i] = -1;
}

// ---------------- sequential (stable) per-expert position scan, single wave
__global__ void scan_kernel(const int* __restrict__ eid, int* __restrict__ slot,
                            int* __restrict__ tok_of) {
  __shared__ int se[N_TOK];  // 32 KiB
  const int tid = threadIdx.x;  // 256
  for (int i = tid; i < N_TOK; i += 256) se[i] = eid[i];
  __syncthreads();
  if (tid >= 64) return;
  int counts[8] = {0, 0, 0, 0, 0, 0, 0, 0};  // wave-uniform
  const unsigned long long lower = (tid == 0) ? 0ull : ((1ull << tid) - 1ull);
  for (int base = 0; base < N_TOK; base += 64) {
    const int t = base + tid;
    const int e = se[t];
    int rank = 0;
#pragma unroll
    for (int ee = 0; ee < 8; ++ee) {
      unsigned long long m = __ballot(e == ee);
      if (e == ee) rank = counts[ee] + __popcll(m & lower);
      counts[ee] += __popcll(m);
    }
    slot[t] = rank < CAP ? rank : CAP;
    if (rank < CAP) tok_of[e * CAP + rank] = t;
  }
}

// ---------------- scatter x rows -> binp (E,CAP,D) bf16; empty rows = 0
__global__ __launch_bounds__(256) void scatter_kernel(const float* __restrict__ x,
                                                      const int* __restrict__ tok_of,
                                                      unsigned short* __restrict__ binp) {
  const int row = blockIdx.x * 4 + (threadIdx.x >> 6);  // E*CAP rows
  const int l = threadIdx.x & 63;
  const int t = tok_of[row];
  unsigned short* dst = binp + (size_t)row * D_DIM;
  if (t >= 0) {
    const float* src = x + (size_t)t * D_DIM;
#pragma unroll
    for (int i = 0; i < 4; ++i) {
      const int d = (i * 64 + l) * 4;
      float4 v = *reinterpret_cast<const float4*>(src + d);
      unsigned short r[4] = {f2bf(v.x), f2bf(v.y), f2bf(v.z), f2bf(v.w)};
      *reinterpret_cast<uint2*>(dst + d) = *reinterpret_cast<uint2*>(r);
    }
  } else {
    uint2 z = {0u, 0u};
#pragma unroll
    for (int i = 0; i < 4; ++i) {
      const int d = (i * 64 + l) * 4;
      *reinterpret_cast<uint2*>(dst + d) = z;
    }
  }
}

// ---------------- async staging: 128x64 bf16 tile via global_load_lds (16B/lane)
// LDS dest is LINEAR [128][8 chunks of 16B]; the XOR swizzle (chunk ^= row&7) is
// realized by pre-swizzling the GLOBAL source column per lane (rule #21):
// lane l writes LDS chunk (row=base+l>>3, col=l&7), so it must fetch global
// chunk col (l&7) ^ (l>>3)  [row&7 == l>>3 since base%8==0].
__device__ inline void stage_tile_async(const unsigned short* __restrict__ g, int ldg, int k0,
                                        unsigned short* lds, int w, int l) {
  const int gcol = (l & 7) ^ (l >> 3);
  const unsigned short* gsrc = g + (size_t)(w * 32 + (l >> 3)) * ldg + k0 + gcol * 8;
#pragma unroll
  for (int it = 0; it < 4; ++it) {
    __builtin_amdgcn_global_load_lds(
        (const __attribute__((address_space(1))) unsigned int*)(gsrc + (size_t)(it * 8) * ldg),
        (__attribute__((address_space(3))) unsigned int*)(lds + (w * 32 + it * 8) * 64),
        16, 0, 0);
  }
}

// read fragment: chunk col is XOR-swizzled by row&7
__device__ inline bf16x8 lds_frag(const unsigned short* lds, int row, int c16) {
  return *reinterpret_cast<const bf16x8*>(lds + row * 64 + (c16 ^ (row & 7)) * 8);
}

// ---------------- ffn1: h = silu(binp@W2) * (binp@W3), bf16 out. grid (H/128, CAP/128, E)
__global__ __launch_bounds__(256, 3) void ffn1_kernel(const unsigned short* __restrict__ binp,
                                                      const unsigned short* __restrict__ w2t,
                                                      const unsigned short* __restrict__ w3t,
                                                      unsigned short* __restrict__ hbuf) {
  __shared__ unsigned short sA[128 * 64], sB2[128 * 64], sB3[128 * 64];
  const int e = blockIdx.z;
  const unsigned short* A  = binp + (size_t)e * CAP * D_DIM + (size_t)blockIdx.y * 128 * D_DIM;
  const unsigned short* B2 = w2t + (size_t)e * H_DIM * D_DIM + (size_t)blockIdx.x * 128 * D_DIM;
  const unsigned short* B3 = w3t + (size_t)e * H_DIM * D_DIM + (size_t)blockIdx.x * 128 * D_DIM;
  unsigned short* H = hbuf + (size_t)e * CAP * H_DIM;
  const int tid = threadIdx.x;
  const int l = tid & 63;
  const int w = tid >> 6, wr = w >> 1, wc = w & 1;
  f32x4 acc2[4][4] = {};
  f32x4 acc3[4][4] = {};
  for (int kt = 0; kt < D_DIM / 64; ++kt) {
    __syncthreads();  // previous compute done before overwrite
    stage_tile_async(A, D_DIM, kt * 64, sA, w, l);
    stage_tile_async(B2, D_DIM, kt * 64, sB2, w, l);
    stage_tile_async(B3, D_DIM, kt * 64, sB3, w, l);
    vm_drain();       // DMA retired before any wave crosses the barrier
    __syncthreads();
#pragma unroll
    for (int kk = 0; kk < 2; ++kk) {
      const int c16 = kk * 4 + (l >> 4);
      bf16x8 af[4], b2f[4], b3f[4];
#pragma unroll
      for (int f = 0; f < 4; ++f) {
        af[f] = lds_frag(sA, wr * 64 + f * 16 + (l & 15), c16);
        b2f[f] = lds_frag(sB2, wc * 64 + f * 16 + (l & 15), c16);
        b3f[f] = lds_frag(sB3, wc * 64 + f * 16 + (l & 15), c16);
      }
#pragma unroll
      for (int fm = 0; fm < 4; ++fm)
#pragma unroll
        for (int fn = 0; fn < 4; ++fn) {
          acc2[fm][fn] = __builtin_amdgcn_mfma_f32_16x16x32_bf16(af[fm], b2f[fn], acc2[fm][fn], 0, 0, 0);
          acc3[fm][fn] = __builtin_amdgcn_mfma_f32_16x16x32_bf16(af[fm], b3f[fn], acc3[fm][fn], 0, 0, 0);
        }
    }
  }
  const int row0 = blockIdx.y * 128 + wr * 64;
  const int col0 = blockIdx.x * 128 + wc * 64;
#pragma unroll
  for (int fm = 0; fm < 4; ++fm)
#pragma unroll
    for (int fn = 0; fn < 4; ++fn)
#pragma unroll
      for (int j = 0; j < 4; ++j) {
        const int row = row0 + fm * 16 + (l >> 4) * 4 + j;
        const int col = col0 + fn * 16 + (l & 15);
        const float v1 = acc2[fm][fn][j];
        const float v2 = acc3[fm][fn][j];
        const float hv = (v1 / (1.0f + __expf(-v1))) * v2;
        H[(size_t)row * H_DIM + col] = f2bf(hv);
      }
}

// ---------------- ffn2: bout = h@W1; fused gather: out[t] = gate[t]*bout. grid (D/128, CAP/128, E)
__global__ __launch_bounds__(256, 4) void ffn2_kernel(const unsigned short* __restrict__ hbuf,
                                                      const unsigned short* __restrict__ w1t,
                                                      const int* __restrict__ tok_of,
                                                      const float* __restrict__ gatew,
                                                      float* __restrict__ out) {
  __shared__ unsigned short sA[128 * 64], sB[128 * 64];
  const int e = blockIdx.z;
  const unsigned short* A = hbuf + (size_t)e * CAP * H_DIM + (size_t)blockIdx.y * 128 * H_DIM;
  const unsigned short* B = w1t + (size_t)e * D_DIM * H_DIM + (size_t)blockIdx.x * 128 * H_DIM;
  const int* tok = tok_of + e * CAP;
  const int tid = threadIdx.x;
  const int l = tid & 63;
  const int w = tid >> 6, wr = w >> 1, wc = w & 1;
  f32x4 acc[4][4] = {};
  for (int kt = 0; kt < H_DIM / 64; ++kt) {
    __syncthreads();
    stage_tile_async(A, H_DIM, kt * 64, sA, w, l);
    stage_tile_async(B, H_DIM, kt * 64, sB, w, l);
    vm_drain();
    __syncthreads();
#pragma unroll
    for (int kk = 0; kk < 2; ++kk) {
      const int c16 = kk * 4 + (l >> 4);
      bf16x8 af[4], bf[4];
#pragma unroll
      for (int f = 0; f < 4; ++f) {
        af[f] = lds_frag(sA, wr * 64 + f * 16 + (l & 15), c16);
        bf[f] = lds_frag(sB, wc * 64 + f * 16 + (l & 15), c16);
      }
#pragma unroll
      for (int fm = 0; fm < 4; ++fm)
#pragma unroll
        for (int fn = 0; fn < 4; ++fn)
          acc[fm][fn] = __builtin_amdgcn_mfma_f32_16x16x32_bf16(af[fm], bf[fn], acc[fm][fn], 0, 0, 0);
    }
  }
  const int row0 = blockIdx.y * 128 + wr * 64;
  const int col0 = blockIdx.x * 128 + wc * 64;
#pragma unroll
  for (int fm = 0; fm < 4; ++fm)
#pragma unroll
    for (int j = 0; j < 4; ++j) {
      const int row = row0 + fm * 16 + (l >> 4) * 4 + j;
      const int t = tok[row];
      if (t >= 0) {
        const float g = gatew[t];
#pragma unroll
        for (int fn = 0; fn < 4; ++fn) {
          const int col = col0 + fn * 16 + (l & 15);
          out[(size_t)t * D_DIM + col] = g * acc[fm][fn][j];
        }
      }
    }
}

// ---------------- overflow tokens (slot >= CAP) -> out = 0
__global__ __launch_bounds__(256) void zero_overflow(const int* __restrict__ slot,
                                                     float* __restrict__ out) {
  const int t = blockIdx.x * 4 + (threadIdx.x >> 6);
  if (slot[t] < CAP) return;
  const int l = threadIdx.x & 63;
  float4 z = {0.f, 0.f, 0.f, 0.f};
#pragma unroll
  for (int i = 0; i < 4; ++i)
    *reinterpret_cast<float4*>(out + (size_t)t * D_DIM + (i * 64 + l) * 4) = z;
}

extern "C" void kernel_launch(void* const* d_in, const int* in_sizes, int n_in,
                              void* d_out, int out_size, void* d_ws, size_t ws_size,
                              hipStream_t stream) {
  const float* x  = (const float*)d_in[0];
  const float* Wg = (const float*)d_in[1];
  const float* bg = (const float*)d_in[2];
  const float* W1 = (const float*)d_in[3];
  const float* W2 = (const float*)d_in[4];
  const float* W3 = (const float*)d_in[5];
  float* out = (float*)d_out;

  char* ws = (char*)d_ws;
  unsigned short* w2t = (unsigned short*)ws; ws += (size_t)E_NUM * H_DIM * D_DIM * 2;
  unsigned short* w3t = (unsigned short*)ws; ws += (size_t)E_NUM * H_DIM * D_DIM * 2;
  unsigned short* w1t = (unsigned short*)ws; ws += (size_t)E_NUM * D_DIM * H_DIM * 2;
  unsigned short* binp = (unsigned short*)ws; ws += (size_t)E_NUM * CAP * D_DIM * 2;
  unsigned short* hbuf = (unsigned short*)ws; ws += (size_t)E_NUM * CAP * H_DIM * 2;
  int* eid = (int*)ws;    ws += (size_t)N_TOK * 4;
  float* gw = (float*)ws; ws += (size_t)N_TOK * 4;
  int* slot = (int*)ws;   ws += (size_t)N_TOK * 4;
  int* tok_of = (int*)ws; ws += (size_t)E_NUM * CAP * 4;

  dim3 tb(256);
  // W2 (E,D,H) -> w2t (E,H,D): R=D rows, C=H cols
  transpose_cvt<<<dim3(H_DIM / 32, D_DIM / 64, E_NUM), tb, 0, stream>>>(W2, w2t, D_DIM, H_DIM);
  // W3 (E,D,H) -> w3t (E,H,D)
  transpose_cvt<<<dim3(H_DIM / 32, D_DIM / 64, E_NUM), tb, 0, stream>>>(W3, w3t, D_DIM, H_DIM);
  // W1 (E,H,D) -> w1t (E,D,H): R=H rows, C=D cols
  transpose_cvt<<<dim3(D_DIM / 32, H_DIM / 64, E_NUM), tb, 0, stream>>>(W1, w1t, H_DIM, D_DIM);

  init_tok<<<(E_NUM * CAP + 255) / 256, 256, 0, stream>>>(tok_of);
  gate_kernel<<<N_TOK / 4, 256, 0, stream>>>(x, Wg, bg, eid, gw);
  scan_kernel<<<1, 256, 0, stream>>>(eid, slot, tok_of);
  scatter_kernel<<<E_NUM * CAP / 4, 256, 0, stream>>>(x, tok_of, binp);
  ffn1_kernel<<<dim3(H_DIM / 128, CAP / 128, E_NUM), 256, 0, stream>>>(binp, w2t, w3t, hbuf);
  ffn2_kernel<<<dim3(D_DIM / 128, CAP / 128, E_NUM), 256, 0, stream>>>(hbuf, w1t, tok_of, gw, out);
  zero_overflow<<<N_TOK / 4, 256, 0, stream>>>(slot, out);
}

// Round 4
// 272.730 us; speedup vs baseline: 1.1451x; 1.1451x over previous
//
#include <hip/hip_runtime.h>

#define N_TOK 8192
#define D_DIM 1024
#define H_DIM 2048
#define E_NUM 8
#define CAP   1280

typedef __attribute__((ext_vector_type(8))) short bf16x8;
typedef __attribute__((ext_vector_type(8))) unsigned short u16x8;
typedef __attribute__((ext_vector_type(4))) float f32x4;

__device__ inline unsigned short f2bf(float f) {
  unsigned u = __float_as_uint(f);
  u += 0x7fffu + ((u >> 16) & 1u);
  return (unsigned short)(u >> 16);
}

// Explicit drain of outstanding global_load_lds DMA before cross-wave LDS reads.
__device__ inline void vm_drain() {
  asm volatile("s_waitcnt vmcnt(0)" ::: "memory");
}

// ---------------- transpose + fp32->bf16: src (B,R,C) f32 -> dst (B,C,R) bf16
__global__ __launch_bounds__(256) void transpose_cvt(const float* __restrict__ src,
                                                     unsigned short* __restrict__ dst,
                                                     int R, int C) {
  __shared__ float tile[64][33];
  const int b = blockIdx.z;
  src += (size_t)b * R * C;
  dst += (size_t)b * R * C;
  const int c0 = blockIdx.x * 32, r0 = blockIdx.y * 64;
  const int tx = threadIdx.x & 31, ty = threadIdx.x >> 5;  // 256 = (32,8)
#pragma unroll
  for (int i = 0; i < 8; ++i)
    tile[ty + i * 8][tx] = src[(size_t)(r0 + ty + i * 8) * C + c0 + tx];
  __syncthreads();
  const int rp = threadIdx.x & 31;      // r-pair index 0..31
  const int cb = threadIdx.x >> 5;      // c base 0..7
#pragma unroll
  for (int it = 0; it < 4; ++it) {
    const int c = cb + it * 8;
    unsigned short v[2] = {f2bf(tile[2 * rp][c]), f2bf(tile[2 * rp + 1][c])};
    *reinterpret_cast<unsigned*>(dst + (size_t)(c0 + c) * R + r0 + 2 * rp) =
        *reinterpret_cast<unsigned*>(v);
  }
}

// ---------------- gating: logits = x@Wg + bg; eid=argmax; gate = softmax(logits)[eid]
__global__ __launch_bounds__(256) void gate_kernel(const float* __restrict__ x,
                                                   const float* __restrict__ Wg,
                                                   const float* __restrict__ bg,
                                                   int* __restrict__ eid,
                                                   float* __restrict__ gatew) {
  __shared__ float wg[E_NUM][D_DIM];  // transposed, 32 KiB
  const int tid = threadIdx.x;
  for (int i = tid; i < D_DIM * E_NUM; i += 256) {
    int d = i >> 3, e = i & 7;
    wg[e][d] = Wg[i];
  }
  __syncthreads();
  const int w = tid >> 6, l = tid & 63;
  const int t = blockIdx.x * 4 + w;
  const float* xr = x + (size_t)t * D_DIM;
  float acc[8] = {0, 0, 0, 0, 0, 0, 0, 0};
#pragma unroll
  for (int i = 0; i < D_DIM / 64; ++i) {
    float xv = xr[l + 64 * i];
#pragma unroll
    for (int e = 0; e < 8; ++e) acc[e] += xv * wg[e][l + 64 * i];
  }
#pragma unroll
  for (int off = 32; off >= 1; off >>= 1) {
#pragma unroll
    for (int e = 0; e < 8; ++e) acc[e] += __shfl_xor(acc[e], off);
  }
  if (l == 0) {
    float best = -1e30f;
    int bi = 0;
#pragma unroll
    for (int e = 0; e < 8; ++e) {
      acc[e] += bg[e];
      if (acc[e] > best) { best = acc[e]; bi = e; }
    }
    float s = 0.f;
#pragma unroll
    for (int e = 0; e < 8; ++e) s += __expf(acc[e] - best);
    eid[t] = bi;
    gatew[t] = 1.f / s;
  }
}

// ---------------- init tok_of to -1
__global__ void init_tok(int* __restrict__ tok_of) {
  int i = blockIdx.x * 256 + threadIdx.x;
  if (i < E_NUM * CAP) tok_of[i] = -1;
}

// ---------------- sequential (stable) per-expert position scan, single wave
__global__ void scan_kernel(const int* __restrict__ eid, int* __restrict__ slot,
                            int* __restrict__ tok_of) {
  __shared__ int se[N_TOK];  // 32 KiB
  const int tid = threadIdx.x;  // 256
  for (int i = tid; i < N_TOK; i += 256) se[i] = eid[i];
  __syncthreads();
  if (tid >= 64) return;
  int counts[8] = {0, 0, 0, 0, 0, 0, 0, 0};  // wave-uniform
  const unsigned long long lower = (tid == 0) ? 0ull : ((1ull << tid) - 1ull);
  for (int base = 0; base < N_TOK; base += 64) {
    const int t = base + tid;
    const int e = se[t];
    int rank = 0;
#pragma unroll
    for (int ee = 0; ee < 8; ++ee) {
      unsigned long long m = __ballot(e == ee);
      if (e == ee) rank = counts[ee] + __popcll(m & lower);
      counts[ee] += __popcll(m);
    }
    slot[t] = rank < CAP ? rank : CAP;
    if (rank < CAP) tok_of[e * CAP + rank] = t;
  }
}

// ---------------- scatter x rows -> binp (E,CAP,D) bf16; empty rows = 0
__global__ __launch_bounds__(256) void scatter_kernel(const float* __restrict__ x,
                                                      const int* __restrict__ tok_of,
                                                      unsigned short* __restrict__ binp) {
  const int row = blockIdx.x * 4 + (threadIdx.x >> 6);  // E*CAP rows
  const int l = threadIdx.x & 63;
  const int t = tok_of[row];
  unsigned short* dst = binp + (size_t)row * D_DIM;
  if (t >= 0) {
    const float* src = x + (size_t)t * D_DIM;
#pragma unroll
    for (int i = 0; i < 4; ++i) {
      const int d = (i * 64 + l) * 4;
      float4 v = *reinterpret_cast<const float4*>(src + d);
      unsigned short r[4] = {f2bf(v.x), f2bf(v.y), f2bf(v.z), f2bf(v.w)};
      *reinterpret_cast<uint2*>(dst + d) = *reinterpret_cast<uint2*>(r);
    }
  } else {
    uint2 z = {0u, 0u};
#pragma unroll
    for (int i = 0; i < 4; ++i) {
      const int d = (i * 64 + l) * 4;
      *reinterpret_cast<uint2*>(dst + d) = z;
    }
  }
}

// ---------------- async staging: 128x64 bf16 tile via global_load_lds (16B/lane)
// Linear LDS dest [128][8x16B chunks]; XOR swizzle realized by pre-swizzling the
// GLOBAL source chunk per lane (rule #21): lane l fetches chunk (l&7)^(l>>3).
__device__ inline void stage_tile_async(const unsigned short* __restrict__ g, int ldg, int k0,
                                        unsigned short* lds, int w, int l) {
  const int gcol = (l & 7) ^ (l >> 3);
  const unsigned short* gsrc = g + (size_t)(w * 32 + (l >> 3)) * ldg + k0 + gcol * 8;
#pragma unroll
  for (int it = 0; it < 4; ++it) {
    __builtin_amdgcn_global_load_lds(
        (const __attribute__((address_space(1))) unsigned int*)(gsrc + (size_t)(it * 8) * ldg),
        (__attribute__((address_space(3))) unsigned int*)(lds + (w * 32 + it * 8) * 64),
        16, 0, 0);
  }
}

// read fragment: chunk col is XOR-swizzled by row&7
__device__ inline bf16x8 lds_frag(const unsigned short* lds, int row, int c16) {
  return *reinterpret_cast<const bf16x8*>(lds + row * 64 + (c16 ^ (row & 7)) * 8);
}

// ---------------- ffn1: h = silu(binp@W2) * (binp@W3), bf16 out. grid (H/128, CAP/128, E)
// launch_bounds min-waves MUST stay 2: acc needs 128 VGPR + ~48 frag; 512/3=170 forces spills.
__global__ __launch_bounds__(256, 2) void ffn1_kernel(const unsigned short* __restrict__ binp,
                                                      const unsigned short* __restrict__ w2t,
                                                      const unsigned short* __restrict__ w3t,
                                                      unsigned short* __restrict__ hbuf) {
  __shared__ unsigned short sA[128 * 64], sB2[128 * 64], sB3[128 * 64];
  const int e = blockIdx.z;
  const unsigned short* A  = binp + (size_t)e * CAP * D_DIM + (size_t)blockIdx.y * 128 * D_DIM;
  const unsigned short* B2 = w2t + (size_t)e * H_DIM * D_DIM + (size_t)blockIdx.x * 128 * D_DIM;
  const unsigned short* B3 = w3t + (size_t)e * H_DIM * D_DIM + (size_t)blockIdx.x * 128 * D_DIM;
  unsigned short* H = hbuf + (size_t)e * CAP * H_DIM;
  const int tid = threadIdx.x;
  const int l = tid & 63;
  const int w = tid >> 6, wr = w >> 1, wc = w & 1;
  f32x4 acc2[4][4] = {};
  f32x4 acc3[4][4] = {};
  for (int kt = 0; kt < D_DIM / 64; ++kt) {
    __syncthreads();  // previous compute done before overwrite
    stage_tile_async(A, D_DIM, kt * 64, sA, w, l);
    stage_tile_async(B2, D_DIM, kt * 64, sB2, w, l);
    stage_tile_async(B3, D_DIM, kt * 64, sB3, w, l);
    vm_drain();       // DMA retired before any wave crosses the barrier
    __syncthreads();
#pragma unroll
    for (int kk = 0; kk < 2; ++kk) {
      const int c16 = kk * 4 + (l >> 4);
      bf16x8 af[4], b2f[4], b3f[4];
#pragma unroll
      for (int f = 0; f < 4; ++f) {
        af[f] = lds_frag(sA, wr * 64 + f * 16 + (l & 15), c16);
        b2f[f] = lds_frag(sB2, wc * 64 + f * 16 + (l & 15), c16);
        b3f[f] = lds_frag(sB3, wc * 64 + f * 16 + (l & 15), c16);
      }
#pragma unroll
      for (int fm = 0; fm < 4; ++fm)
#pragma unroll
        for (int fn = 0; fn < 4; ++fn) {
          acc2[fm][fn] = __builtin_amdgcn_mfma_f32_16x16x32_bf16(af[fm], b2f[fn], acc2[fm][fn], 0, 0, 0);
          acc3[fm][fn] = __builtin_amdgcn_mfma_f32_16x16x32_bf16(af[fm], b3f[fn], acc3[fm][fn], 0, 0, 0);
        }
    }
  }
  const int row0 = blockIdx.y * 128 + wr * 64;
  const int col0 = blockIdx.x * 128 + wc * 64;
#pragma unroll
  for (int fm = 0; fm < 4; ++fm)
#pragma unroll
    for (int fn = 0; fn < 4; ++fn)
#pragma unroll
      for (int j = 0; j < 4; ++j) {
        const int row = row0 + fm * 16 + (l >> 4) * 4 + j;
        const int col = col0 + fn * 16 + (l & 15);
        const float v1 = acc2[fm][fn][j];
        const float v2 = acc3[fm][fn][j];
        const float hv = (v1 / (1.0f + __expf(-v1))) * v2;
        H[(size_t)row * H_DIM + col] = f2bf(hv);
      }
}

// ---------------- ffn2: bout = h@W1; fused gather: out[t] = gate[t]*bout. grid (D/128, CAP/128, E)
__global__ __launch_bounds__(256, 2) void ffn2_kernel(const unsigned short* __restrict__ hbuf,
                                                      const unsigned short* __restrict__ w1t,
                                                      const int* __restrict__ tok_of,
                                                      const float* __restrict__ gatew,
                                                      float* __restrict__ out) {
  __shared__ unsigned short sA[128 * 64], sB[128 * 64];
  const int e = blockIdx.z;
  const unsigned short* A = hbuf + (size_t)e * CAP * H_DIM + (size_t)blockIdx.y * 128 * H_DIM;
  const unsigned short* B = w1t + (size_t)e * D_DIM * H_DIM + (size_t)blockIdx.x * 128 * H_DIM;
  const int* tok = tok_of + e * CAP;
  const int tid = threadIdx.x;
  const int l = tid & 63;
  const int w = tid >> 6, wr = w >> 1, wc = w & 1;
  f32x4 acc[4][4] = {};
  for (int kt = 0; kt < H_DIM / 64; ++kt) {
    __syncthreads();
    stage_tile_async(A, H_DIM, kt * 64, sA, w, l);
    stage_tile_async(B, H_DIM, kt * 64, sB, w, l);
    vm_drain();
    __syncthreads();
#pragma unroll
    for (int kk = 0; kk < 2; ++kk) {
      const int c16 = kk * 4 + (l >> 4);
      bf16x8 af[4], bf[4];
#pragma unroll
      for (int f = 0; f < 4; ++f) {
        af[f] = lds_frag(sA, wr * 64 + f * 16 + (l & 15), c16);
        bf[f] = lds_frag(sB, wc * 64 + f * 16 + (l & 15), c16);
      }
#pragma unroll
      for (int fm = 0; fm < 4; ++fm)
#pragma unroll
        for (int fn = 0; fn < 4; ++fn)
          acc[fm][fn] = __builtin_amdgcn_mfma_f32_16x16x32_bf16(af[fm], bf[fn], acc[fm][fn], 0, 0, 0);
    }
  }
  const int row0 = blockIdx.y * 128 + wr * 64;
  const int col0 = blockIdx.x * 128 + wc * 64;
#pragma unroll
  for (int fm = 0; fm < 4; ++fm)
#pragma unroll
    for (int j = 0; j < 4; ++j) {
      const int row = row0 + fm * 16 + (l >> 4) * 4 + j;
      const int t = tok[row];
      if (t >= 0) {
        const float g = gatew[t];
#pragma unroll
        for (int fn = 0; fn < 4; ++fn) {
          const int col = col0 + fn * 16 + (l & 15);
          out[(size_t)t * D_DIM + col] = g * acc[fm][fn][j];
        }
      }
    }
}

// ---------------- overflow tokens (slot >= CAP) -> out = 0
__global__ __launch_bounds__(256) void zero_overflow(const int* __restrict__ slot,
                                                     float* __restrict__ out) {
  const int t = blockIdx.x * 4 + (threadIdx.x >> 6);
  if (slot[t] < CAP) return;
  const int l = threadIdx.x & 63;
  float4 z = {0.f, 0.f, 0.f, 0.f};
#pragma unroll
  for (int i = 0; i < 4; ++i)
    *reinterpret_cast<float4*>(out + (size_t)t * D_DIM + (i * 64 + l) * 4) = z;
}

extern "C" void kernel_launch(void* const* d_in, const int* in_sizes, int n_in,
                              void* d_out, int out_size, void* d_ws, size_t ws_size,
                              hipStream_t stream) {
  const float* x  = (const float*)d_in[0];
  const float* Wg = (const float*)d_in[1];
  const float* bg = (const float*)d_in[2];
  const float* W1 = (const float*)d_in[3];
  const float* W2 = (const float*)d_in[4];
  const float* W3 = (const float*)d_in[5];
  float* out = (float*)d_out;

  char* ws = (char*)d_ws;
  unsigned short* w2t = (unsigned short*)ws; ws += (size_t)E_NUM * H_DIM * D_DIM * 2;
  unsigned short* w3t = (unsigned short*)ws; ws += (size_t)E_NUM * H_DIM * D_DIM * 2;
  unsigned short* w1t = (unsigned short*)ws; ws += (size_t)E_NUM * D_DIM * H_DIM * 2;
  unsigned short* binp = (unsigned short*)ws; ws += (size_t)E_NUM * CAP * D_DIM * 2;
  unsigned short* hbuf = (unsigned short*)ws; ws += (size_t)E_NUM * CAP * H_DIM * 2;
  int* eid = (int*)ws;    ws += (size_t)N_TOK * 4;
  float* gw = (float*)ws; ws += (size_t)N_TOK * 4;
  int* slot = (int*)ws;   ws += (size_t)N_TOK * 4;
  int* tok_of = (int*)ws; ws += (size_t)E_NUM * CAP * 4;

  dim3 tb(256);
  // W2 (E,D,H) -> w2t (E,H,D): R=D rows, C=H cols
  transpose_cvt<<<dim3(H_DIM / 32, D_DIM / 64, E_NUM), tb, 0, stream>>>(W2, w2t, D_DIM, H_DIM);
  // W3 (E,D,H) -> w3t (E,H,D)
  transpose_cvt<<<dim3(H_DIM / 32, D_DIM / 64, E_NUM), tb, 0, stream>>>(W3, w3t, D_DIM, H_DIM);
  // W1 (E,H,D) -> w1t (E,D,H): R=H rows, C=D cols
  transpose_cvt<<<dim3(D_DIM / 32, H_DIM / 64, E_NUM), tb, 0, stream>>>(W1, w1t, H_DIM, D_DIM);

  init_tok<<<(E_NUM * CAP + 255) / 256, 256, 0, stream>>>(tok_of);
  gate_kernel<<<N_TOK / 4, 256, 0, stream>>>(x, Wg, bg, eid, gw);
  scan_kernel<<<1, 256, 0, stream>>>(eid, slot, tok_of);
  scatter_kernel<<<E_NUM * CAP / 4, 256, 0, stream>>>(x, tok_of, binp);
  ffn1_kernel<<<dim3(H_DIM / 128, CAP / 128, E_NUM), 256, 0, stream>>>(binp, w2t, w3t, hbuf);
  ffn2_kernel<<<dim3(D_DIM / 128, CAP / 128, E_NUM), 256, 0, stream>>>(hbuf, w1t, tok_of, gw, out);
  zero_overflow<<<N_TOK / 4, 256, 0, stream>>>(slot, out);
}